// Round 20
// baseline (124.555 us; speedup 1.0000x reference)
//
#include <hip/hip_runtime.h>
#include <hip/hip_bf16.h>
#include <math.h>

// Problem constants
#define Bc 4
#define Nc 1024
#define Ec 1024
#define Hc 16
#define Dc 64
#define Mc 4096                    // B*N rows
#define OUT0_ELEMS 4194304         // B*H*N*D
#define SCRATCH_OFF 58720256       // float offset into attn region for bf16 scratch
#define NTK 32                     // K-tiles (BK=32)

typedef __attribute__((ext_vector_type(4))) float f32x4;
typedef __attribute__((ext_vector_type(16))) float f32x16;
typedef __attribute__((ext_vector_type(8))) short s16x8;

__device__ __forceinline__ short f2bf(float f) {
    union { __bf16 h; short s; } c; c.h = (__bf16)f; return c.s;
}

typedef const __attribute__((address_space(1))) char gch;
typedef __attribute__((address_space(3))) char lch;
__device__ __forceinline__ void gload16(const short* g, short* l) {
    __builtin_amdgcn_global_load_lds((gch*)g, (lch*)l, 16, 0, 0);
}

// ---------------------------------------------------------------------------
// L0 cvt: W (Wq,Wk) + X rows of batches 0,1 (first 2M elems of Xq and Xk).
// 3072 blocks x 2048 elems.
// ---------------------------------------------------------------------------
__global__ __launch_bounds__(256)
void cvt0_kernel(const float* __restrict__ wq, const float* __restrict__ wk,
                 const float* __restrict__ xq, const float* __restrict__ xk,
                 short* __restrict__ xall, short* __restrict__ wall)
{
    const int b = blockIdx.x;
    const float* src; short* dst; size_t ofs;
    if (b < 512)       { src = wq; dst = wall;           ofs = (size_t)b * 2048; }
    else if (b < 1024) { src = wk; dst = wall + 1048576; ofs = (size_t)(b - 512) * 2048; }
    else if (b < 2048) { src = xq; dst = xall;           ofs = (size_t)(b - 1024) * 2048; }
    else               { src = xk; dst = xall + 4194304; ofs = (size_t)(b - 2048) * 2048; }
    const size_t i = ofs + (size_t)threadIdx.x * 8;
    f32x4 a = *(const f32x4*)(src + i);
    f32x4 c = *(const f32x4*)(src + i + 4);
    s16x8 o;
    o[0] = f2bf(a[0]); o[1] = f2bf(a[1]); o[2] = f2bf(a[2]); o[3] = f2bf(a[3]);
    o[4] = f2bf(c[0]); o[5] = f2bf(c[1]); o[6] = f2bf(c[2]); o[7] = f2bf(c[3]);
    *(s16x8*)(dst + i) = o;
}

// ---------------------------------------------------------------------------
// Mega kernel, 512 threads. Block-type dispatch by bid:
//   [0, nV)            -> V-projection (R15/R19 write-ahead reg-staged dbuf)
//   [nV, nV+nP)        -> Q/K proj, 128x128 tile, 8 waves (2Mx4N, 64x32/wave),
//                         2-buf counted-vmcnt(2) pipeline, XOR-swizzled LDS.
//                         pBase selects the row half (bx in [pBase, pBase+16)).
//   [nV+nP, nV+nP+nA)  -> attn scores+softmax (R19 exact), aBase = bh base.
//   rest               -> cvt of Xq/Xk rows b2,b3 (2M elems each src).
// LDS union: max(V 32KB, P 32KB, A 37.9KB) = 37888 B -> 4 blocks/CU.
// ---------------------------------------------------------------------------
__global__ __launch_bounds__(512, 4)
void mega_kernel(int nV, int nP, int pBase, int nA, int aBase,
                 const short* __restrict__ qws_r, const short* __restrict__ kws_r,
                 short* __restrict__ qws, short* __restrict__ kws,
                 float* __restrict__ attnOut,
                 const float* __restrict__ vin, const float* __restrict__ Wv,
                 const float* __restrict__ bv, float* __restrict__ out0,
                 const short* __restrict__ xall, const short* __restrict__ wall,
                 const float* __restrict__ bq, const float* __restrict__ bk,
                 const float* __restrict__ xqf, const float* __restrict__ xkf)
{
    __shared__ __align__(16) char smemRaw[37888];

    const int bid = blockIdx.x;
    const int t   = threadIdx.x;
    const int lane = t & 63;

    if (bid < nV) {
        // ============ V-projection: 128x128 tile, write-ahead dbuf ========
        short (*lsA)[128 * 32] = (short (*)[128 * 32])(smemRaw);
        short (*lsB)[128 * 32] = (short (*)[128 * 32])(smemRaw + 16384);
        const int vb = bid;
        const int bm = (vb & 31) * 128;
        const int bn = (vb >> 5) * 128;
        const int w  = t >> 6;
        const int wr = w >> 2;
        const int wc = w & 3;
        const int li = lane & 15, g = lane >> 4;

        const int r0 = t >> 2;
        const int c2 = t & 3;
        const float* Xs = vin + (size_t)(bm + r0) * Ec + c2 * 8;
        const float* Ws = Wv  + (size_t)(bn + r0) * Ec + c2 * 8;
        const int aoff = r0 * 32 + ((c2 ^ ((r0 >> 1) & 3)) * 8);

        f32x4 acc[4][2];
#pragma unroll
        for (int i = 0; i < 4; ++i)
#pragma unroll
            for (int j = 0; j < 2; ++j)
                acc[i][j] = (f32x4){0.f, 0.f, 0.f, 0.f};

        f32x4 eA0, eA1, eB0, eB1;
        f32x4 oA0, oA1, oB0, oB1;

#define VLOAD(a0, a1, b0, b1, kt)                                             \
        {                                                                     \
            const float* pa = Xs + (kt) * 32;                                 \
            const float* pb = Ws + (kt) * 32;                                 \
            a0 = *(const f32x4*)(pa); a1 = *(const f32x4*)(pa + 4);           \
            b0 = *(const f32x4*)(pb); b1 = *(const f32x4*)(pb + 4);           \
        }

#define VWRITE(buf, a0, a1, b0, b1)                                           \
        {                                                                     \
            s16x8 ha, hb;                                                     \
            _Pragma("unroll")                                                 \
            for (int i = 0; i < 4; ++i) {                                     \
                ha[i] = f2bf(a0[i]); ha[i + 4] = f2bf(a1[i]);                 \
                hb[i] = f2bf(b0[i]); hb[i + 4] = f2bf(b1[i]);                 \
            }                                                                 \
            *(s16x8*)&lsA[buf][aoff] = ha;                                    \
            *(s16x8*)&lsB[buf][aoff] = hb;                                    \
        }

#define VCOMPUTE(buf)                                                         \
        {                                                                     \
            s16x8 aF[4], bF[2];                                               \
            _Pragma("unroll")                                                 \
            for (int mt = 0; mt < 4; ++mt) {                                  \
                const int r = wr * 64 + mt * 16 + li;                         \
                aF[mt] = *(const s16x8*)&lsA[buf][r * 32 + ((g ^ ((r >> 1) & 3)) * 8)]; \
            }                                                                 \
            _Pragma("unroll")                                                 \
            for (int nt = 0; nt < 2; ++nt) {                                  \
                const int r = wc * 32 + nt * 16 + li;                         \
                bF[nt] = *(const s16x8*)&lsB[buf][r * 32 + ((g ^ ((r >> 1) & 3)) * 8)]; \
            }                                                                 \
            _Pragma("unroll")                                                 \
            for (int mt = 0; mt < 4; ++mt)                                    \
                _Pragma("unroll")                                             \
                for (int nt = 0; nt < 2; ++nt)                                \
                    acc[mt][nt] = __builtin_amdgcn_mfma_f32_16x16x32_bf16(    \
                        aF[mt], bF[nt], acc[mt][nt], 0, 0, 0);                \
        }

        VLOAD(eA0, eA1, eB0, eB1, 0);
        VLOAD(oA0, oA1, oB0, oB1, 1);
        VWRITE(0, eA0, eA1, eB0, eB1);
        VLOAD(eA0, eA1, eB0, eB1, 2);
        asm volatile("s_waitcnt lgkmcnt(0)" ::: "memory");
        __builtin_amdgcn_s_barrier();

        for (int tt = 0; tt < NTK; tt += 2) {
            VCOMPUTE(0);
            if (tt + 1 < NTK) {
                VWRITE(1, oA0, oA1, oB0, oB1);
                if (tt + 3 < NTK) VLOAD(oA0, oA1, oB0, oB1, tt + 3);
            }
            asm volatile("s_waitcnt lgkmcnt(0)" ::: "memory");
            __builtin_amdgcn_s_barrier();

            if (tt + 1 < NTK) {
                VCOMPUTE(1);
                if (tt + 2 < NTK) {
                    VWRITE(0, eA0, eA1, eB0, eB1);
                    if (tt + 4 < NTK) VLOAD(eA0, eA1, eB0, eB1, tt + 4);
                }
                asm volatile("s_waitcnt lgkmcnt(0)" ::: "memory");
                __builtin_amdgcn_s_barrier();
            }
        }
#undef VCOMPUTE
#undef VWRITE
#undef VLOAD

#pragma unroll
        for (int nt = 0; nt < 2; ++nt) {
            const int col = bn + wc * 32 + nt * 16 + li;
            const float bcol = bv[col];
            const int h = col >> 6, d = col & 63;
#pragma unroll
            for (int mt = 0; mt < 4; ++mt) {
#pragma unroll
                for (int r = 0; r < 4; ++r) {
                    const int row = bm + wr * 64 + mt * 16 + g * 4 + r;
                    const int bb = row >> 10, n = row & 1023;
                    out0[((size_t)(bb * Hc + h) * Nc + n) * Dc + d] =
                        acc[mt][nt][r] + bcol;
                }
            }
        }
        return;
    }

    if (bid < nV + nP) {
        // ============ Q/K projection: 128x128 tile, 8 waves, 2-buf ========
        short (*lpA)[128 * 32] = (short (*)[128 * 32])(smemRaw);
        short (*lpB)[128 * 32] = (short (*)[128 * 32])(smemRaw + 16384);

        const int pb  = bid - nV;                 // 0..255
        const int sel = pb >> 7;                  // 0 -> Q, 1 -> K
        const int r7  = pb & 127;
        const int bx  = pBase + (r7 >> 3);        // row block (16 per half)
        const int by  = r7 & 7;                   // col block
        const short* X = xall + (size_t)sel * 4194304;
        const short* W = wall + (size_t)sel * 1048576;
        const float* bias = sel ? bk : bq;
        short* dst = sel ? kws : qws;

        const int bm = bx * 128;
        const int bn = by * 128;
        const int w  = t >> 6;                    // 0..7
        const int wr = w >> 2;                    // 0..1 (64-row half)
        const int wcn = w & 3;                    // 0..3 (32-col quarter)
        const int li = lane & 15, g = lane >> 4;

        // staging: per wave 1 A-gload + 1 B-gload (16 rows x 64B each)
        const int srow = w * 16 + (lane >> 2);    // tile row
        const int c_   = lane & 3;
        const int cg   = (c_ ^ ((srow >> 1) & 3)) * 8;

        f32x4 acc[4][2];
#pragma unroll
        for (int i = 0; i < 4; ++i)
#pragma unroll
            for (int j = 0; j < 2; ++j)
                acc[i][j] = (f32x4){0.f, 0.f, 0.f, 0.f};

#define PSTAGE(buf, kt)                                                       \
        {                                                                     \
            gload16(X + (size_t)(bm + srow) * Ec + (kt) * 32 + cg,            \
                    &lpA[buf][(w * 16) * 32]);                                \
            gload16(W + (size_t)(bn + srow) * Ec + (kt) * 32 + cg,            \
                    &lpB[buf][(w * 16) * 32]);                                \
        }

        PSTAGE(0, 0);
        PSTAGE(1, 1);

        for (int kt = 0; kt < NTK; ++kt) {
            const int cur = kt & 1;
            if (kt < NTK - 1) {
                asm volatile("s_waitcnt vmcnt(2)" ::: "memory");
            } else {
                asm volatile("s_waitcnt vmcnt(0)" ::: "memory");
            }
            __builtin_amdgcn_s_barrier();

            s16x8 aF[4], bF[2];
#pragma unroll
            for (int mt = 0; mt < 4; ++mt) {
                const int r = wr * 64 + mt * 16 + li;
                aF[mt] = *(const s16x8*)&lpA[cur][r * 32 + ((g ^ ((r >> 1) & 3)) * 8)];
            }
#pragma unroll
            for (int nt = 0; nt < 2; ++nt) {
                const int r = wcn * 32 + nt * 16 + li;
                bF[nt] = *(const s16x8*)&lpB[cur][r * 32 + ((g ^ ((r >> 1) & 3)) * 8)];
            }
#pragma unroll
            for (int mt = 0; mt < 4; ++mt)
#pragma unroll
                for (int nt = 0; nt < 2; ++nt)
                    acc[mt][nt] = __builtin_amdgcn_mfma_f32_16x16x32_bf16(
                        aF[mt], bF[nt], acc[mt][nt], 0, 0, 0);

            asm volatile("s_waitcnt lgkmcnt(0)" ::: "memory");
            __builtin_amdgcn_s_barrier();
            if (kt + 2 < NTK) PSTAGE(cur, kt + 2);
        }
#undef PSTAGE

#pragma unroll
        for (int nt = 0; nt < 2; ++nt) {
            const int col = bn + wcn * 32 + nt * 16 + li;
            const float bcol = bias[col];
            const int h = col >> 6, d = col & 63;
#pragma unroll
            for (int mt = 0; mt < 4; ++mt) {
#pragma unroll
                for (int r = 0; r < 4; ++r) {
                    const int row = bm + wr * 64 + mt * 16 + g * 4 + r;
                    const int bb = row >> 10, n = row & 1023;
                    dst[((size_t)(bb * Hc + h) * Nc + n) * Dc + d] =
                        f2bf(acc[mt][nt][r] + bcol);
                }
            }
        }
        return;
    }

    if (bid < nV + nP + nA) {
        // ===================== attn: scores + softmax (R19) ================
        short* lsK = (short*)smemRaw;                          // [256][64]
        short* lsQ = (short*)(smemRaw + 32768);                // [32][64]
        float (*red)[32] = (float (*)[32])(smemRaw + 36864);   // [8][32]

        const int abid = bid - nV - nP;             // 0..1023
        const int rb  = (abid >> 3) & 31;
        const int bh  = aBase + (((abid & 7) << 2) | (abid >> 8));
        const int w  = t >> 6;
        const int li = lane & 31;
        const int hi = lane >> 5;

        const short* Qb = qws_r + (size_t)bh * (Nc * Dc);
        const short* Kb = kws_r + (size_t)bh * (Nc * Dc);

        const int gcs = ((lane & 7) ^ (lane >> 3)) * 8;
        const int gr8 = lane >> 3;

        if (w < 4)
            gload16(Qb + (size_t)(rb * 32 + w * 8 + gr8) * Dc + gcs,
                    &lsQ[(w * 8) * Dc]);

#define STAGEK(tile)                                                          \
        {                                                                     \
            _Pragma("unroll")                                                 \
            for (int j = 0; j < 4; ++j) {                                     \
                const int rb8 = w * 32 + j * 8;                               \
                gload16(Kb + (size_t)((tile) * 256 + rb8 + gr8) * Dc + gcs,   \
                        &lsK[rb8 * Dc]);                                      \
            }                                                                 \
        }

        STAGEK(0);
        __syncthreads();

        s16x8 qF[4];
#pragma unroll
        for (int s = 0; s < 4; ++s) {
            const int slot = (hi + 2 * s) ^ (li & 7);
            qF[s] = *(const s16x8*)&lsQ[li * Dc + slot * 8];
        }

        f32x16 acc[4];
#pragma unroll
        for (int i = 0; i < 4; ++i) acc[i] = (f32x16)(0.f);

#pragma unroll
        for (int tile = 0; tile < 4; ++tile) {
            const int lr = w * 32 + li;
#pragma unroll
            for (int s = 0; s < 4; ++s) {
                const int slot = (hi + 2 * s) ^ (li & 7);
                s16x8 kf = *(const s16x8*)&lsK[lr * Dc + slot * 8];
                acc[tile] = __builtin_amdgcn_mfma_f32_32x32x16_bf16(
                    qF[s], kf, acc[tile], 0, 0, 0);
            }
            __syncthreads();
            if (tile < 3) {
                STAGEK(tile + 1);
                __syncthreads();
            }
        }
#undef STAGEK

        const float c = 1.44269504f / 32.0f;
        float sm[16];
#pragma unroll
        for (int r = 0; r < 16; ++r) sm[r] = 0.f;
#pragma unroll
        for (int ct = 0; ct < 4; ++ct) {
#pragma unroll
            for (int r = 0; r < 16; ++r) {
                float p = __builtin_amdgcn_exp2f(acc[ct][r] * c);
                acc[ct][r] = p;
                sm[r] += p;
            }
        }
#pragma unroll
        for (int r = 0; r < 16; ++r) {
#pragma unroll
            for (int off = 1; off < 32; off <<= 1)
                sm[r] += __shfl_xor(sm[r], off);
        }

        if (li == 0) {
#pragma unroll
            for (int r = 0; r < 16; ++r)
                red[w][(r & 3) + 8 * (r >> 2) + 4 * hi] = sm[r];
        }
        __syncthreads();
#pragma unroll
        for (int r = 0; r < 16; ++r) {
            const int row = (r & 3) + 8 * (r >> 2) + 4 * hi;
            float s = red[0][row] + red[1][row] + red[2][row] + red[3][row] +
                      red[4][row] + red[5][row] + red[6][row] + red[7][row];
            sm[r] = 1.0f / s;
        }

        float* outp = attnOut + (size_t)bh * (Nc * Nc) + (size_t)(rb * 32) * Nc;
#pragma unroll
        for (int ct = 0; ct < 4; ++ct) {
            const int col = ct * 256 + w * 32 + li;
#pragma unroll
            for (int r = 0; r < 16; ++r) {
                const int row = (r & 3) + 8 * (r >> 2) + 4 * hi;
                __builtin_nontemporal_store(acc[ct][r] * sm[r],
                                            &outp[(size_t)row * Nc + col]);
            }
        }
        return;
    }

    // ===================== cvt-rest: Xq/Xk rows b2,b3 ======================
    {
        const int cb = bid - nV - nP - nA;          // 0..1023
        const int seg = (cb >> 9);                  // 0 -> Xq, 1 -> Xk
        const float* src = seg ? xkf : xqf;
        short* dstx = (short*)(xall + (seg ? 4194304 : 0));
        const size_t i = 2097152 + (size_t)(cb & 511) * 4096 + (size_t)t * 8;
        f32x4 a = *(const f32x4*)(src + i);
        f32x4 c2 = *(const f32x4*)(src + i + 4);
        s16x8 o;
        o[0] = f2bf(a[0]); o[1] = f2bf(a[1]); o[2] = f2bf(a[2]); o[3] = f2bf(a[3]);
        o[4] = f2bf(c2[0]); o[5] = f2bf(c2[1]); o[6] = f2bf(c2[2]); o[7] = f2bf(c2[3]);
        *(s16x8*)(dstx + i) = o;
    }
}

extern "C" void kernel_launch(void* const* d_in, const int* in_sizes, int n_in,
                              void* d_out, int out_size, void* d_ws, size_t ws_size,
                              hipStream_t stream) {
    const float* q  = (const float*)d_in[0];
    const float* k  = (const float*)d_in[1];
    const float* v  = (const float*)d_in[2];
    const float* Wq = (const float*)d_in[3];
    const float* bq = (const float*)d_in[4];
    const float* Wk = (const float*)d_in[5];
    const float* bk = (const float*)d_in[6];
    const float* Wv = (const float*)d_in[7];
    const float* bv = (const float*)d_in[8];

    float* out0 = (float*)d_out;                      // (B,H,N,D) fp32
    float* attn = (float*)d_out + OUT0_ELEMS;         // (B,H,N,N) fp32

    // bf16 scratch (20 MB) in the tail of the attn region. Written by
    // cvt0/L1-cvt, read by P blocks (L1, L2). Attn blocks for bh>=32 (L3)
    // overwrite this region only after all P reads completed (L2 boundary).
    short* s16  = (short*)(attn + SCRATCH_OFF);
    short* xall = s16;                                // Xq|Xk bf16 (8M)
    short* wall = s16 + 8388608;                      // Wq|Wk bf16 (2M)

    short* qws = (short*)d_ws;                        // bf16 Q [b][h][n][d]
    short* kws = qws + (size_t)Mc * Ec;               // bf16 K [b][h][n][d]

    // L0: W + X halves b0,b1
    cvt0_kernel<<<3072, 256, 0, stream>>>(Wq, Wk, q, k, xall, wall);
    // L1: V-proj (256) | P half 0 (256) | cvt-rest (1024)
    mega_kernel<<<1536, 512, 0, stream>>>(
        256, 256, 0, 0, 0,
        qws, kws, qws, kws, attn, v, Wv, bv, out0,
        xall, wall, bq, bk, q, k);
    // L2: P half 1 (256) | attn half 0 (1024)
    mega_kernel<<<1280, 512, 0, stream>>>(
        0, 256, 16, 1024, 0,
        qws, kws, qws, kws, attn, v, Wv, bv, out0,
        xall, wall, bq, bk, q, k);
    // L3: attn half 1 (1024)
    mega_kernel<<<1024, 512, 0, stream>>>(
        0, 0, 0, 1024, 32,
        qws, kws, qws, kws, attn, v, Wv, bv, out0,
        xall, wall, bq, bk, q, k);
}

// Round 21
// 115.446 us; speedup vs baseline: 1.0789x; 1.0789x over previous
//
#include <hip/hip_runtime.h>
#include <hip/hip_bf16.h>
#include <math.h>

// Problem constants
#define Bc 4
#define Nc 1024
#define Ec 1024
#define Hc 16
#define Dc 64
#define Mc 4096                    // B*N rows
#define OUT0_ELEMS 4194304         // B*H*N*D
#define ATTN_ELEMS 67108864ULL     // B*H*N*N floats
#define SCRATCH_OFF 58720256       // float offset into attn region for bf16 scratch
#define NTK 32                     // K-tiles (BK=32)

typedef __attribute__((ext_vector_type(4))) float f32x4;
typedef __attribute__((ext_vector_type(16))) float f32x16;
typedef __attribute__((ext_vector_type(8))) short s16x8;

// Hardware bf16 convert (compiler pairs into v_cvt_pk_bf16_f32)
__device__ __forceinline__ short f2bf(float f) {
    union { __bf16 h; short s; } c; c.h = (__bf16)f; return c.s;
}

// async global->LDS, 16B per lane; LDS dest = wave-uniform base + lane*16
typedef const __attribute__((address_space(1))) char gch;
typedef __attribute__((address_space(3))) char lch;
__device__ __forceinline__ void gload16(const short* g, short* l) {
    __builtin_amdgcn_global_load_lds((gch*)g, (lch*)l, 16, 0, 0);
}

// ---------------------------------------------------------------------------
// fp32 -> bf16 pre-pass: Q/K inputs only (Xq, Xk, Wq, Wk). ~10us.
// ---------------------------------------------------------------------------
__global__ __launch_bounds__(256)
void cvt_kernel(const float* __restrict__ xq, const float* __restrict__ xk,
                const float* __restrict__ wq, const float* __restrict__ wk,
                short* __restrict__ dst)
{
    const int which = blockIdx.y;
    const float* src; size_t n, off;
    switch (which) {
      case 0:  src = xq; n = 4194304; off = 0;       break;
      case 1:  src = xk; n = 4194304; off = 4194304; break;
      case 2:  src = wq; n = 1048576; off = 8388608; break;
      default: src = wk; n = 1048576; off = 9437184; break;
    }
    const size_t i = ((size_t)blockIdx.x * 256 + threadIdx.x) * 8;
    if (i >= n) return;
    f32x4 a = *(const f32x4*)(src + i);
    f32x4 b = *(const f32x4*)(src + i + 4);
    s16x8 o;
    o[0] = f2bf(a[0]); o[1] = f2bf(a[1]); o[2] = f2bf(a[2]); o[3] = f2bf(a[3]);
    o[4] = f2bf(b[0]); o[5] = f2bf(b[1]); o[6] = f2bf(b[2]); o[7] = f2bf(b[3]);
    *(s16x8*)(dst + off + i) = o;
}

// ---------------------------------------------------------------------------
// Q/K projection GEMM (R7 structure, proven; sel in {0,1}).
// ---------------------------------------------------------------------------
__global__ __launch_bounds__(256)
void proj_kernel(const short* __restrict__ xall, const short* __restrict__ wall,
                 const float* __restrict__ bq, const float* __restrict__ bk,
                 short* __restrict__ qws, short* __restrict__ kws)
{
    const int sel = blockIdx.z;
    const short* X = xall + (size_t)sel * 4194304;
    const short* W = wall + (size_t)sel * 1048576;
    const float* bias = (sel == 0) ? bq : bk;

    __shared__ __align__(16) short lA[3][128 * 32];
    __shared__ __align__(16) short lB[3][128 * 32];

    const int t    = threadIdx.x;
    const int lane = t & 63;
    const int w    = t >> 6;
    const int wr   = w >> 1, wc = w & 1;      // 2x2 wave grid, 64x64 each
    const int li   = lane & 15, g = lane >> 4;
    const int bm   = blockIdx.x * 128;
    const int bn   = blockIdx.y * 128;

    const int sr = lane >> 2;
    const int c_ = lane & 3;

    f32x4 acc[4][4];
#pragma unroll
    for (int i = 0; i < 4; ++i)
#pragma unroll
        for (int j = 0; j < 4; ++j)
            acc[i][j] = (f32x4){0.f, 0.f, 0.f, 0.f};

#define STAGE(buf, kt)                                                        \
    {                                                                         \
        const int kb = (kt) * 32;                                             \
        _Pragma("unroll")                                                     \
        for (int j = 0; j < 2; ++j) {                                         \
            const int row = w * 32 + j * 16 + sr;                             \
            const int cg  = (c_ ^ ((row >> 1) & 3)) * 8;                      \
            gload16(X + (size_t)(bm + row) * Ec + kb + cg,                    \
                    &lA[buf][(w * 32 + j * 16) * 32]);                        \
            gload16(W + (size_t)(bn + row) * Ec + kb + cg,                    \
                    &lB[buf][(w * 32 + j * 16) * 32]);                        \
        }                                                                     \
    }

    STAGE(0, 0);
    STAGE(1, 1);
    asm volatile("s_waitcnt vmcnt(4)" ::: "memory");
    __builtin_amdgcn_s_barrier();

    for (int kt = 0; kt < NTK; ++kt) {
        const int cur = kt % 3;
        if (kt + 2 < NTK) STAGE((kt + 2) % 3, kt + 2);

        s16x8 aF[4], bF[4];
#pragma unroll
        for (int mt = 0; mt < 4; ++mt) {
            const int r = wr * 64 + mt * 16 + li;
            aF[mt] = *(const s16x8*)&lA[cur][r * 32 + ((g ^ ((r >> 1) & 3)) * 8)];
        }
#pragma unroll
        for (int nt = 0; nt < 4; ++nt) {
            const int r = wc * 64 + nt * 16 + li;
            bF[nt] = *(const s16x8*)&lB[cur][r * 32 + ((g ^ ((r >> 1) & 3)) * 8)];
        }
#pragma unroll
        for (int mt = 0; mt < 4; ++mt)
#pragma unroll
            for (int nt = 0; nt < 4; ++nt)
                acc[mt][nt] = __builtin_amdgcn_mfma_f32_16x16x32_bf16(
                    aF[mt], bF[nt], acc[mt][nt], 0, 0, 0);

        if (kt + 2 < NTK) {
            asm volatile("s_waitcnt vmcnt(4)" ::: "memory");
        } else {
            asm volatile("s_waitcnt vmcnt(0)" ::: "memory");
        }
        __builtin_amdgcn_s_barrier();
    }
#undef STAGE

    short* dstBF = (sel == 0) ? qws : kws;
#pragma unroll
    for (int nt = 0; nt < 4; ++nt) {
        const int col = bn + wc * 64 + nt * 16 + li;
        const float bcol = bias[col];
        const int h = col >> 6, d = col & 63;
#pragma unroll
        for (int mt = 0; mt < 4; ++mt) {
#pragma unroll
            for (int r = 0; r < 4; ++r) {
                const int row = bm + wr * 64 + mt * 16 + g * 4 + r;
                const int bb = row >> 10, n = row & 1023;
                const size_t off = ((size_t)(bb * Hc + h) * Nc + n) * Dc + d;
                dstBF[off] = f2bf(acc[mt][nt][r] + bcol);
            }
        }
    }
}

// ---------------------------------------------------------------------------
// Fused kernel:
//   bid <  256 -> V-projection (R14 write-ahead reg-staged dbuf; reads
//                 ORIGINAL fp32 v/Wv; uses 32KB of the shared union).
//   bid >= 256 -> scores+softmax; K and Q staged through LDS via coalesced
//                 global_load_lds (8 full-line TA requests per instr instead
//                 of 64 scattered 16B segments), fragments read from LDS
//                 with chunk-XOR swizzle (slot = chunk ^ (row&7), source
//                 pre-swizzled). K in 4 single-buffered 256-row tiles.
//                 Softmax + scattered NT stores (proven best).
// LDS: 32KB lsK + 4KB lsQ + 1KB red = 37KB -> 4 blocks/CU kept.
// ---------------------------------------------------------------------------
__global__ __launch_bounds__(512, 4)
void fused_kernel(const short* __restrict__ qws, const short* __restrict__ kws,
                  float* __restrict__ attnOut,
                  const float* __restrict__ vin, const float* __restrict__ Wv,
                  const float* __restrict__ bv, float* __restrict__ out0)
{
    __shared__ __align__(16) char smemRaw[37888];

    const int bid = blockIdx.x;
    const int t   = threadIdx.x;
    const int lane = t & 63;

    if (bid < 256) {
        // ============ V-projection: 128x128 tile, write-ahead dbuf ========
        short (*lsA)[128 * 32] = (short (*)[128 * 32])(smemRaw);
        short (*lsB)[128 * 32] = (short (*)[128 * 32])(smemRaw + 16384);

        const int bm = (bid & 31) * 128;
        const int bn = (bid >> 5) * 128;
        const int w  = t >> 6;
        const int wr = w >> 2;               // 0..1: 64-row half
        const int wc = w & 3;                // 0..3: 32-col quarter
        const int li = lane & 15, g = lane >> 4;

        const int r0 = t >> 2;
        const int c2 = t & 3;
        const float* Xs = vin + (size_t)(bm + r0) * Ec + c2 * 8;
        const float* Ws = Wv  + (size_t)(bn + r0) * Ec + c2 * 8;
        const int aoff = r0 * 32 + ((c2 ^ ((r0 >> 1) & 3)) * 8);

        f32x4 acc[4][2];
#pragma unroll
        for (int i = 0; i < 4; ++i)
#pragma unroll
            for (int j = 0; j < 2; ++j)
                acc[i][j] = (f32x4){0.f, 0.f, 0.f, 0.f};

        f32x4 eA0, eA1, eB0, eB1;
        f32x4 oA0, oA1, oB0, oB1;

#define VLOAD(a0, a1, b0, b1, kt)                                             \
        {                                                                     \
            const float* pa = Xs + (kt) * 32;                                 \
            const float* pb = Ws + (kt) * 32;                                 \
            a0 = *(const f32x4*)(pa); a1 = *(const f32x4*)(pa + 4);           \
            b0 = *(const f32x4*)(pb); b1 = *(const f32x4*)(pb + 4);           \
        }

#define VWRITE(buf, a0, a1, b0, b1)                                           \
        {                                                                     \
            s16x8 ha, hb;                                                     \
            _Pragma("unroll")                                                 \
            for (int i = 0; i < 4; ++i) {                                     \
                ha[i] = f2bf(a0[i]); ha[i + 4] = f2bf(a1[i]);                 \
                hb[i] = f2bf(b0[i]); hb[i + 4] = f2bf(b1[i]);                 \
            }                                                                 \
            *(s16x8*)&lsA[buf][aoff] = ha;                                    \
            *(s16x8*)&lsB[buf][aoff] = hb;                                    \
        }

#define VCOMPUTE(buf)                                                         \
        {                                                                     \
            s16x8 aF[4], bF[2];                                               \
            _Pragma("unroll")                                                 \
            for (int mt = 0; mt < 4; ++mt) {                                  \
                const int r = wr * 64 + mt * 16 + li;                         \
                aF[mt] = *(const s16x8*)&lsA[buf][r * 32 + ((g ^ ((r >> 1) & 3)) * 8)]; \
            }                                                                 \
            _Pragma("unroll")                                                 \
            for (int nt = 0; nt < 2; ++nt) {                                  \
                const int r = wc * 32 + nt * 16 + li;                         \
                bF[nt] = *(const s16x8*)&lsB[buf][r * 32 + ((g ^ ((r >> 1) & 3)) * 8)]; \
            }                                                                 \
            _Pragma("unroll")                                                 \
            for (int mt = 0; mt < 4; ++mt)                                    \
                _Pragma("unroll")                                             \
                for (int nt = 0; nt < 2; ++nt)                                \
                    acc[mt][nt] = __builtin_amdgcn_mfma_f32_16x16x32_bf16(    \
                        aF[mt], bF[nt], acc[mt][nt], 0, 0, 0);                \
        }

        VLOAD(eA0, eA1, eB0, eB1, 0);
        VLOAD(oA0, oA1, oB0, oB1, 1);
        VWRITE(0, eA0, eA1, eB0, eB1);
        VLOAD(eA0, eA1, eB0, eB1, 2);
        asm volatile("s_waitcnt lgkmcnt(0)" ::: "memory");
        __builtin_amdgcn_s_barrier();

        for (int tt = 0; tt < NTK; tt += 2) {
            VCOMPUTE(0);
            if (tt + 1 < NTK) {
                VWRITE(1, oA0, oA1, oB0, oB1);
                if (tt + 3 < NTK) VLOAD(oA0, oA1, oB0, oB1, tt + 3);
            }
            asm volatile("s_waitcnt lgkmcnt(0)" ::: "memory");
            __builtin_amdgcn_s_barrier();

            if (tt + 1 < NTK) {
                VCOMPUTE(1);
                if (tt + 2 < NTK) {
                    VWRITE(0, eA0, eA1, eB0, eB1);
                    if (tt + 4 < NTK) VLOAD(eA0, eA1, eB0, eB1, tt + 4);
                }
                asm volatile("s_waitcnt lgkmcnt(0)" ::: "memory");
                __builtin_amdgcn_s_barrier();
            }
        }
#undef VCOMPUTE
#undef VWRITE
#undef VLOAD

#pragma unroll
        for (int nt = 0; nt < 2; ++nt) {
            const int col = bn + wc * 32 + nt * 16 + li;
            const float bcol = bv[col];
            const int h = col >> 6, d = col & 63;
#pragma unroll
            for (int mt = 0; mt < 4; ++mt) {
#pragma unroll
                for (int r = 0; r < 4; ++r) {
                    const int row = bm + wr * 64 + mt * 16 + g * 4 + r;
                    const int bb = row >> 10, n = row & 1023;
                    out0[((size_t)(bb * Hc + h) * Nc + n) * Dc + d] =
                        acc[mt][nt][r] + bcol;
                }
            }
        }
        return;
    }

    // ===================== attn: scores + softmax ==========================
    short* lsK = (short*)smemRaw;                          // [256][64] = 32KB
    short* lsQ = (short*)(smemRaw + 32768);                // [32][64]  = 4KB
    float (*red)[32] = (float (*)[32])(smemRaw + 36864);   // [8][32]

    const int abid = bid - 256;                 // 0..2047
    const int rb  = (abid >> 3) & 31;           // 32-row block
    const int bh  = ((abid & 7) << 3) | (abid >> 8);  // head: abid%8 == bh>>3
    const int w  = t >> 6;                      // 0..7
    const int li = lane & 31;
    const int hi = lane >> 5;

    const short* Qb = qws + (size_t)bh * (Nc * Dc);
    const short* Kb = kws + (size_t)bh * (Nc * Dc);

    // source pre-swizzle: LDS slot cs of row r holds global chunk cs^(r&7).
    const int gcs = ((lane & 7) ^ (lane >> 3)) * 8;   // shorts
    const int gr8 = lane >> 3;                        // row within 8

    // ---- stage Q (waves 0-3, 8 rows each) + K tile 0 (coalesced) ----
    if (w < 4)
        gload16(Qb + (size_t)(rb * 32 + w * 8 + gr8) * Dc + gcs,
                &lsQ[(w * 8) * Dc]);

#define STAGEK(tile)                                                          \
    {                                                                         \
        _Pragma("unroll")                                                     \
        for (int j = 0; j < 4; ++j) {                                         \
            const int rb8 = w * 32 + j * 8;                                   \
            gload16(Kb + (size_t)((tile) * 256 + rb8 + gr8) * Dc + gcs,       \
                    &lsK[rb8 * Dc]);                                          \
        }                                                                     \
    }

    STAGEK(0);
    __syncthreads();

    // ---- Q fragments from LDS (chunk-XOR swizzled reads) ----
    s16x8 qF[4];
#pragma unroll
    for (int s = 0; s < 4; ++s) {
        const int slot = (hi + 2 * s) ^ (li & 7);
        qF[s] = *(const s16x8*)&lsQ[li * Dc + slot * 8];
    }

    f32x16 acc[4];
#pragma unroll
    for (int i = 0; i < 4; ++i) acc[i] = (f32x16)(0.f);

    // ---- 4 K-tiles of 256 rows; wave w owns cols tile*256 + w*32 + li ----
#pragma unroll
    for (int tile = 0; tile < 4; ++tile) {
        const int lr = w * 32 + li;             // LDS row within tile
#pragma unroll
        for (int s = 0; s < 4; ++s) {
            const int slot = (hi + 2 * s) ^ (li & 7);
            s16x8 kf = *(const s16x8*)&lsK[lr * Dc + slot * 8];
            acc[tile] = __builtin_amdgcn_mfma_f32_32x32x16_bf16(
                qF[s], kf, acc[tile], 0, 0, 0);
        }
        __syncthreads();                        // all reads of lsK done
        if (tile < 3) {
            STAGEK(tile + 1);
            __syncthreads();                    // tile+1 staged
        }
    }
#undef STAGEK

    // exp + row partial sum (no max subtraction; scores tiny in exp2 space)
    const float c = 1.44269504f / 32.0f;   // log2(e)/SCALE, SCALE = 32
    float sm[16];
#pragma unroll
    for (int r = 0; r < 16; ++r) sm[r] = 0.f;
#pragma unroll
    for (int ct = 0; ct < 4; ++ct) {
#pragma unroll
        for (int r = 0; r < 16; ++r) {
            float p = __builtin_amdgcn_exp2f(acc[ct][r] * c);
            acc[ct][r] = p;
            sm[r] += p;
        }
    }
#pragma unroll
    for (int r = 0; r < 16; ++r) {
#pragma unroll
        for (int off = 1; off < 32; off <<= 1)
            sm[r] += __shfl_xor(sm[r], off);
    }

    if (li == 0) {
#pragma unroll
        for (int r = 0; r < 16; ++r)
            red[w][(r & 3) + 8 * (r >> 2) + 4 * hi] = sm[r];
    }
    __syncthreads();
#pragma unroll
    for (int r = 0; r < 16; ++r) {
        const int row = (r & 3) + 8 * (r >> 2) + 4 * hi;
        float s = red[0][row] + red[1][row] + red[2][row] + red[3][row] +
                  red[4][row] + red[5][row] + red[6][row] + red[7][row];
        sm[r] = 1.0f / s;
    }

    // NT stores (proven best: scattered full-128B-line segments)
    float* outp = attnOut + (size_t)bh * (Nc * Nc) + (size_t)(rb * 32) * Nc;
#pragma unroll
    for (int ct = 0; ct < 4; ++ct) {
        const int col = ct * 256 + w * 32 + li;
#pragma unroll
        for (int r = 0; r < 16; ++r) {
            const int row = (r & 3) + 8 * (r >> 2) + 4 * hi;
            __builtin_nontemporal_store(acc[ct][r] * sm[r],
                                        &outp[(size_t)row * Nc + col]);
        }
    }
}

extern "C" void kernel_launch(void* const* d_in, const int* in_sizes, int n_in,
                              void* d_out, int out_size, void* d_ws, size_t ws_size,
                              hipStream_t stream) {
    const float* q  = (const float*)d_in[0];
    const float* k  = (const float*)d_in[1];
    const float* v  = (const float*)d_in[2];
    const float* Wq = (const float*)d_in[3];
    const float* bq = (const float*)d_in[4];
    const float* Wk = (const float*)d_in[5];
    const float* bk = (const float*)d_in[6];
    const float* Wv = (const float*)d_in[7];
    const float* bv = (const float*)d_in[8];

    float* out0 = (float*)d_out;                      // (B,H,N,D) fp32
    float* attn = (float*)d_out + OUT0_ELEMS;         // (B,H,N,N) fp32

    // bf16 Q/K scratch (20 MB) in the TAIL of the attn region: read only by
    // proj_kernel, which completes before the fused kernel; fused attn
    // blocks then freely overwrite it. V path reads only original inputs.
    short* s16  = (short*)(attn + SCRATCH_OFF);
    short* xall = s16;                                // Xq|Xk bf16
    short* wall = s16 + 8388608;                      // Wq|Wk bf16

    short* qws = (short*)d_ws;                        // bf16 Q [b][h][n][d]
    short* kws = qws + (size_t)Mc * Ec;               // bf16 K [b][h][n][d]

    cvt_kernel<<<dim3(2048, 4), 256, 0, stream>>>(q, k, Wq, Wk, s16);
    proj_kernel<<<dim3(32, 8, 2), 256, 0, stream>>>(
        xall, wall, bq, bk, qws, kws);
    fused_kernel<<<2304, 512, 0, stream>>>(qws, kws, attn, v, Wv, bv, out0);
}